// Round 9
// baseline (1002.854 us; speedup 1.0000x reference)
//
#include <hip/hip_runtime.h>
#include <stdint.h>

typedef _Float16 f16;
typedef __attribute__((ext_vector_type(8))) _Float16 f16x8;
typedef __attribute__((ext_vector_type(4))) _Float16 f16x4;
typedef __attribute__((ext_vector_type(4))) float f32x4;

// async global->LDS, 16B per lane. LDS dest is wave-uniform base (+lane*16 in HW).
__device__ __forceinline__ void gload16(void* lds, const void* gc) {
  void* g = const_cast<void*>(gc);
  __builtin_amdgcn_global_load_lds((__attribute__((address_space(1))) void*)g,
                                   (__attribute__((address_space(3))) void*)lds,
                                   16, 0, 0);
}

// ---------------- f32 -> f16 cast (plain) ----------------
__global__ __launch_bounds__(256) void k_cast(const float* __restrict__ in,
                                              f16* __restrict__ out, int n4) {
  int stride = gridDim.x * blockDim.x;
  for (int i = blockIdx.x * blockDim.x + threadIdx.x; i < n4; i += stride) {
    float4 v = ((const float4*)in)[i];
    f16x4 o;
    o[0] = (f16)v.x; o[1] = (f16)v.y; o[2] = (f16)v.z; o[3] = (f16)v.w;
    ((f16x4*)out)[i] = o;
  }
}

// 4 independent cast jobs selected by blockIdx.y (equal sizes)
__global__ __launch_bounds__(256) void k_cast4(const float* __restrict__ s0, const float* __restrict__ s1,
                                               const float* __restrict__ s2, const float* __restrict__ s3,
                                               f16* __restrict__ d0, f16* __restrict__ d1,
                                               f16* __restrict__ d2, f16* __restrict__ d3, int n4) {
  const int which = blockIdx.y;
  const float* in = which == 0 ? s0 : which == 1 ? s1 : which == 2 ? s2 : s3;
  f16* out = which == 0 ? d0 : which == 1 ? d1 : which == 2 ? d2 : d3;
  int stride = gridDim.x * blockDim.x;
  for (int i = blockIdx.x * blockDim.x + threadIdx.x; i < n4; i += stride) {
    float4 v = ((const float4*)in)[i];
    f16x4 o;
    o[0] = (f16)v.x; o[1] = (f16)v.y; o[2] = (f16)v.z; o[3] = (f16)v.w;
    ((f16x4*)out)[i] = o;
  }
}

// 2 independent cast jobs selected by blockIdx.y
__global__ __launch_bounds__(256) void k_cast2w(const float* __restrict__ s0, const float* __restrict__ s1,
                                                f16* __restrict__ d0, f16* __restrict__ d1, int n4) {
  const int which = blockIdx.y;
  const float* in = which == 0 ? s0 : s1;
  f16* out = which == 0 ? d0 : d1;
  int stride = gridDim.x * blockDim.x;
  for (int i = blockIdx.x * blockDim.x + threadIdx.x; i < n4; i += stride) {
    float4 v = ((const float4*)in)[i];
    f16x4 o;
    o[0] = (f16)v.x; o[1] = (f16)v.y; o[2] = (f16)v.z; o[3] = (f16)v.w;
    ((f16x4*)out)[i] = o;
  }
}

// ---------------- V transpose: [BH][L][128] -> [BH][128][L] ----------------
__global__ __launch_bounds__(256) void k_transpose_v(const f16* __restrict__ vp,
                                                     f16* __restrict__ vt) {
  __shared__ __attribute__((aligned(16))) f16 tile[64][66];
  const int lt = blockIdx.x, dt = blockIdx.y, bh = blockIdx.z;
  const int t = threadIdx.x;
  const int r = t >> 3, c = 8 * (t & 7);
  const f16* src = vp + ((size_t)bh * 2048 + lt * 64) * 128 + dt * 64;
#pragma unroll
  for (int i = 0; i < 2; ++i) {
    union { f16x8 v; unsigned u[4]; } uu;
    uu.v = *(const f16x8*)&src[(size_t)(i * 32 + r) * 128 + c];
#pragma unroll
    for (int j = 0; j < 4; ++j)
      *(unsigned*)&tile[i * 32 + r][c + 2 * j] = uu.u[j];
  }
  __syncthreads();
  f16* dst = vt + ((size_t)bh * 128 + dt * 64) * 2048 + lt * 64;
#pragma unroll
  for (int i = 0; i < 2; ++i) {
    const int dr = i * 32 + r;
    f16x8 o;
#pragma unroll
    for (int e = 0; e < 8; ++e) o[e] = tile[c + e][dr];
    *(f16x8*)&dst[(size_t)dr * 2048 + c] = o;
  }
}

// ---------------- final fuse: out = f32(x1b) + p0 + p1 ----------------
__global__ __launch_bounds__(256) void k_fuseout(const f16* __restrict__ x1b,
                                                 const float* __restrict__ p0,
                                                 const float* __restrict__ p1,
                                                 float* __restrict__ out, int n4) {
  int stride = gridDim.x * blockDim.x;
  for (int i = blockIdx.x * blockDim.x + threadIdx.x; i < n4; i += stride) {
    float4 a = ((const float4*)p0)[i];
    float4 b = ((const float4*)p1)[i];
    f16x4 xb = ((const f16x4*)x1b)[i];
    float4 o;
    o.x = (float)xb[0] + a.x + b.x;
    o.y = (float)xb[1] + a.y + b.y;
    o.z = (float)xb[2] + a.z + b.z;
    o.w = (float)xb[3] + a.w + b.w;
    ((float4*)out)[i] = o;
  }
}

// ---------------- NT GEMM: C[M,N] = A[M,K] @ B[N,K]^T, fused epilogues ----------------
// EPI 0: QKV -> which=gcol>>11: 0,1 -> outb/outb_lo (hi+lo split storage) at
//        which*8M in [B,H,L,DH] layout; 2 -> outv (plain f16) same layout.
// EPI 1: Wo   -> outb = f16(res[idx] + C)
// EPI 2: Up   -> outb = f16(relu(C + bias[col]))
// EPI 3: Down partial -> (z ? outf2 : outf)[idx] = C   (f32, no residual)
template <int EPI, int SPLITOUT, int BK>
__global__ __launch_bounds__(256, 4) void gemm_nt(const f16* __restrict__ A,
                                                  const f16* __restrict__ B,
                                                  int Kit, int ld, int N,
                                                  const float* __restrict__ res,
                                                  const float* __restrict__ bias,
                                                  float* __restrict__ outf,
                                                  float* __restrict__ outf2,
                                                  f16* __restrict__ outb,
                                                  f16* __restrict__ outb_lo,
                                                  f16* __restrict__ outv) {
  constexpr int TSZ = 128 * BK;
  constexpr int CH  = 2048;
  constexpr int RPC = CH / BK;
  constexpr int NCH = 128 / RPC;
  constexpr int CW  = BK / 8;
  __shared__ __attribute__((aligned(16))) f16 As[TSZ];
  __shared__ __attribute__((aligned(16))) f16 Bs[TSZ];
  const int t = threadIdx.x;
  const int l = t & 63;
  const int w = t >> 6;
  const int wr = w >> 1, wc = w & 1;

  // XCD-aware bijective swizzle (nwg % 8 == 0 for all our grids)
  const int nwg = gridDim.x * gridDim.y;
  const int id = blockIdx.y * gridDim.x + blockIdx.x;
  const int sw = (id & 7) * (nwg >> 3) + (id >> 3);
  const int bn = sw % gridDim.x;
  const int bm = sw / gridDim.x;
  const int k0 = blockIdx.z * Kit;

  f32x4 acc[4][4] = {};

  const size_t aoff = (size_t)bm * 128 * ld + k0;
  const size_t boff = (size_t)bn * 128 * ld + k0;

  const int sr = t / CW;
  const int sc = 8 * (t % CW);
  const int lbase = w * 512;

  const int lr = l & 15, lq = l >> 4;
  const int nk = Kit / BK;
  for (int kt = 0; kt < nk; ++kt) {
    const size_t gbase = (size_t)kt * BK + (size_t)sr * ld + sc;
#pragma unroll
    for (int j = 0; j < NCH; ++j) {
      gload16(As + j * CH + lbase, A + aoff + (size_t)j * RPC * ld + gbase);
      gload16(Bs + j * CH + lbase, B + boff + (size_t)j * RPC * ld + gbase);
    }
    __syncthreads();
#pragma unroll
    for (int kk = 0; kk < BK / 32; ++kk) {
      f16x8 af[4], bfr[4];
#pragma unroll
      for (int m = 0; m < 4; ++m)
        af[m] = *(const f16x8*)&As[(wr * 64 + m * 16 + lr) * BK + kk * 32 + 8 * lq];
#pragma unroll
      for (int n = 0; n < 4; ++n)
        bfr[n] = *(const f16x8*)&Bs[(wc * 64 + n * 16 + lr) * BK + kk * 32 + 8 * lq];
#pragma unroll
      for (int m = 0; m < 4; ++m)
#pragma unroll
        for (int n = 0; n < 4; ++n)
          acc[m][n] = __builtin_amdgcn_mfma_f32_16x16x32_f16(af[m], bfr[n], acc[m][n], 0, 0, 0);
    }
    __syncthreads();
  }

  const size_t QKS = (size_t)8 << 20;
#pragma unroll
  for (int m = 0; m < 4; ++m) {
#pragma unroll
    for (int r = 0; r < 4; ++r) {
      const int grow = bm * 128 + wr * 64 + m * 16 + lq * 4 + r;
#pragma unroll
      for (int n = 0; n < 4; ++n) {
        const int gcol = bn * 128 + wc * 64 + n * 16 + lr;
        const float v = acc[m][n][r];
        if constexpr (EPI == 0) {
          const int which = gcol >> 11;
          const int hcol = gcol & 2047;
          const int bb = grow >> 11, ll = grow & 2047;
          const int hh = hcol >> 7, dh = hcol & 127;
          const size_t idx = ((size_t)((bb * 16 + hh) * 2048 + ll) << 7) + dh;
          const f16 hv = (f16)v;
          if (which == 2) {
            outv[idx] = hv;
          } else {
            outb[which * QKS + idx] = hv;
            if constexpr (SPLITOUT) outb_lo[which * QKS + idx] = (f16)(v - (float)hv);
          }
        } else if constexpr (EPI == 1) {
          const size_t idx = (size_t)grow * N + gcol;
          outb[idx] = (f16)(res[idx] + v);
        } else if constexpr (EPI == 2) {
          const size_t idx = (size_t)grow * N + gcol;
          outb[idx] = (f16)fmaxf(v + bias[gcol], 0.f);
        } else {
          const size_t idx = (size_t)grow * N + gcol;
          (blockIdx.z ? outf2 : outf)[idx] = v;
        }
      }
    }
  }
}

// ---------------- causal flash attention ----------------
// Paired complementary q-tiles (qtA=31-bx, qtB=bx) with MERGED inner loops:
// each K/V fragment LDS read feeds both q-tile sets (halves B-operand reads
// in the shared phase). Split-precision QK^T (3-pass), defer-max rescale.
__global__ __launch_bounds__(256) void k_attn(const f16* __restrict__ q_hi,
                                              const f16* __restrict__ q_lo,
                                              const f16* __restrict__ k_hi,
                                              const f16* __restrict__ k_lo,
                                              const f16* __restrict__ vtp,
                                              f16* __restrict__ op) {
  __shared__ __attribute__((aligned(16))) f16 Ks_hi[64 * 136];
  __shared__ __attribute__((aligned(16))) f16 Ks_lo[64 * 136];
  __shared__ __attribute__((aligned(16))) f16 Vs[128 * 72];
  __shared__ __attribute__((aligned(16))) f16 PsA[4][16 * 72];
  __shared__ __attribute__((aligned(16))) f16 PsB[4][16 * 72];
  const int t = threadIdx.x, l = t & 63, w = t >> 6;
  const int qtA = 31 - (int)blockIdx.x;  // 16..31
  const int qtB = (int)blockIdx.x;       // 15..0
  const int bh = blockIdx.y;
  const int qA0 = qtA * 64, qB0 = qtB * 64;
  const int lr = l & 15, lq = l >> 4;

  const f16* qhp = q_hi + (size_t)bh * 2048 * 128;
  const f16* qlp = q_lo + (size_t)bh * 2048 * 128;
  const f16* khp = k_hi + (size_t)bh * 2048 * 128;
  const f16* klp = k_lo + (size_t)bh * 2048 * 128;
  const f16* vhp = vtp + (size_t)bh * 128 * 2048;

  const int krow = t >> 4, kcol8 = 8 * (t & 15);
  const int vrow = t >> 3, vcol8 = 8 * (t & 7);

  f16x8 aqhA[4], aqlA[4], aqhB[4], aqlB[4];
#pragma unroll
  for (int c = 0; c < 4; ++c) {
    const size_t qiA = (size_t)(qA0 + w * 16 + lr) * 128 + c * 32 + 8 * lq;
    const size_t qiB = (size_t)(qB0 + w * 16 + lr) * 128 + c * 32 + 8 * lq;
    aqhA[c] = *(const f16x8*)&qhp[qiA];
    aqlA[c] = *(const f16x8*)&qlp[qiA];
    aqhB[c] = *(const f16x8*)&qhp[qiB];
    aqlB[c] = *(const f16x8*)&qlp[qiB];
  }

  f32x4 accA[8] = {}, accB[8] = {};
  float mrA[4], srA[4], mrB[4], srB[4];
#pragma unroll
  for (int r = 0; r < 4; ++r) {
    mrA[r] = -1e30f; srA[r] = 0.f;
    mrB[r] = -1e30f; srB[r] = 0.f;
  }

  f16x8 kregh[4], kregl[4], vreg[4];
  auto load_tile = [&](int kt) {
#pragma unroll
    for (int i = 0; i < 4; ++i) {
      const size_t ki = (size_t)(kt * 64 + i * 16 + krow) * 128 + kcol8;
      kregh[i] = *(const f16x8*)&khp[ki];
      kregl[i] = *(const f16x8*)&klp[ki];
      vreg[i] = *(const f16x8*)&vhp[(size_t)(i * 32 + vrow) * 2048 + kt * 64 + vcol8];
    }
  };
  load_tile(0);

  // softmax + P-store for one q-set (unshared VALU work); defer-max rescale.
  auto softmax = [&](f32x4 (&s)[4], f32x4 (&acc)[8], float (&mr)[4], float (&sr)[4],
                     f16 (&Pw)[16 * 72]) {
    float mx[4];
#pragma unroll
    for (int r = 0; r < 4; ++r) {
      float m = fmaxf(fmaxf(s[0][r], s[1][r]), fmaxf(s[2][r], s[3][r]));
#pragma unroll
      for (int off = 1; off < 16; off <<= 1)
        m = fmaxf(m, __shfl_xor(m, off));
      mx[r] = m;
    }
    bool grew = false;
#pragma unroll
    for (int r = 0; r < 4; ++r) grew = grew || (mx[r] > mr[r] + 8.f);
    if (__any(grew)) {  // rescale to new max (wave-uniform branch)
      float scale[4];
#pragma unroll
      for (int r = 0; r < 4; ++r) {
        const float mnew = fmaxf(mr[r], mx[r]);
        scale[r] = __expf(mr[r] - mnew);
        mr[r] = mnew;
        sr[r] *= scale[r];
      }
#pragma unroll
      for (int nt = 0; nt < 8; ++nt)
#pragma unroll
        for (int r = 0; r < 4; ++r)
          acc[nt][r] *= scale[r];
    }
    float tsum[4] = {0.f, 0.f, 0.f, 0.f};
#pragma unroll
    for (int nt = 0; nt < 4; ++nt)
#pragma unroll
      for (int r = 0; r < 4; ++r) {
        const float p = __expf(s[nt][r] - mr[r]);  // bounded by e^8 when deferred
        tsum[r] += p;
        Pw[(lq * 4 + r) * 72 + nt * 16 + lr] = (f16)p;
      }
#pragma unroll
    for (int r = 0; r < 4; ++r) {
      float ts = tsum[r];
#pragma unroll
      for (int off = 1; off < 16; off <<= 1)
        ts += __shfl_xor(ts, off);
      sr[r] += ts;
    }
  };

  for (int kt = 0; kt <= qtA; ++kt) {
    __syncthreads();  // prior tile's LDS reads done
#pragma unroll
    for (int i = 0; i < 4; ++i) {
      const int li = (i * 16 + krow) * 136 + kcol8;
      *(f16x8*)&Ks_hi[li] = kregh[i];
      *(f16x8*)&Ks_lo[li] = kregl[i];
      *(f16x8*)&Vs[(i * 32 + vrow) * 72 + vcol8] = vreg[i];
    }
    __syncthreads();
    if (kt < qtA) load_tile(kt + 1);  // next-tile HBM latency hides under compute

    const bool doB = (kt <= qtB);

    // --- merged QK^T: each K-fragment read feeds both q-sets ---
    f32x4 sA[4], sB[4];
    __builtin_amdgcn_s_setprio(1);
#pragma unroll
    for (int nt = 0; nt < 4; ++nt) {
      f32x4 zhA = {}, zlA = {}, zhB = {}, zlB = {};
#pragma unroll
      for (int kc = 0; kc < 4; ++kc) {
        const int li = (nt * 16 + lr) * 136 + kc * 32 + 8 * lq;
        f16x8 bh_ = *(const f16x8*)&Ks_hi[li];
        f16x8 bl_ = *(const f16x8*)&Ks_lo[li];
        zhA = __builtin_amdgcn_mfma_f32_16x16x32_f16(aqhA[kc], bh_, zhA, 0, 0, 0);
        zlA = __builtin_amdgcn_mfma_f32_16x16x32_f16(aqlA[kc], bh_, zlA, 0, 0, 0);
        zlA = __builtin_amdgcn_mfma_f32_16x16x32_f16(aqhA[kc], bl_, zlA, 0, 0, 0);
        if (doB) {
          zhB = __builtin_amdgcn_mfma_f32_16x16x32_f16(aqhB[kc], bh_, zhB, 0, 0, 0);
          zlB = __builtin_amdgcn_mfma_f32_16x16x32_f16(aqlB[kc], bh_, zlB, 0, 0, 0);
          zlB = __builtin_amdgcn_mfma_f32_16x16x32_f16(aqhB[kc], bl_, zlB, 0, 0, 0);
        }
      }
#pragma unroll
      for (int r = 0; r < 4; ++r) {
        sA[nt][r] = zhA[r] + zlA[r];
        sB[nt][r] = zhB[r] + zlB[r];
      }
    }
    __builtin_amdgcn_s_setprio(0);

    // causal masks (diagonal tiles only)
    if (kt == qtA) {
#pragma unroll
      for (int nt = 0; nt < 4; ++nt)
#pragma unroll
        for (int r = 0; r < 4; ++r)
          if (kt * 64 + nt * 16 + lr > qA0 + w * 16 + lq * 4 + r) sA[nt][r] = -1e30f;
    }
    if (doB && kt == qtB) {
#pragma unroll
      for (int nt = 0; nt < 4; ++nt)
#pragma unroll
        for (int r = 0; r < 4; ++r)
          if (kt * 64 + nt * 16 + lr > qB0 + w * 16 + lq * 4 + r) sB[nt][r] = -1e30f;
    }

    softmax(sA, accA, mrA, srA, PsA[w]);
    if (doB) softmax(sB, accB, mrB, srB, PsB[w]);

    // --- merged PV: each V-fragment read feeds both q-sets ---
    __builtin_amdgcn_s_setprio(1);
#pragma unroll
    for (int kc = 0; kc < 2; ++kc) {
      f16x8 apA = *(const f16x8*)&PsA[w][lr * 72 + kc * 32 + 8 * lq];
      f16x8 apB = *(const f16x8*)&PsB[w][lr * 72 + kc * 32 + 8 * lq];
#pragma unroll
      for (int nt = 0; nt < 8; ++nt) {
        f16x8 bv = *(const f16x8*)&Vs[(nt * 16 + lr) * 72 + kc * 32 + 8 * lq];
        accA[nt] = __builtin_amdgcn_mfma_f32_16x16x32_f16(apA, bv, accA[nt], 0, 0, 0);
        if (doB) accB[nt] = __builtin_amdgcn_mfma_f32_16x16x32_f16(apB, bv, accB[nt], 0, 0, 0);
      }
    }
    __builtin_amdgcn_s_setprio(0);
  }

  const int bb = bh >> 4, hh = bh & 15;
  auto wout = [&](f32x4 (&acc)[8], float (&sr)[4], int q0) {
#pragma unroll
    for (int r = 0; r < 4; ++r) {
      const float inv = 1.f / sr[r];
      const size_t row = (size_t)(bb * 2048 + q0 + w * 16 + lq * 4 + r);
#pragma unroll
      for (int nt = 0; nt < 8; ++nt)
        op[row * 2048 + hh * 128 + nt * 16 + lr] = (f16)(acc[nt][r] * inv);
    }
  };
  wout(accA, srA, qA0);
  wout(accB, srB, qB0);
}

extern "C" void kernel_launch(void* const* d_in, const int* in_sizes, int n_in,
                              void* d_out, int out_size, void* d_ws, size_t ws_size,
                              hipStream_t stream) {
  const float* x   = (const float*)d_in[0];
  const float* Wq  = (const float*)d_in[2];
  const float* Wk  = (const float*)d_in[3];
  const float* Wv  = (const float*)d_in[4];
  const float* Wo  = (const float*)d_in[5];
  const float* Wup = (const float*)d_in[6];
  const float* bup = (const float*)d_in[7];
  const float* Wdn = (const float*)d_in[8];
  float* out = (float*)d_out;

  const size_t M1 = 1u << 20;
  f16* W = (f16*)d_ws;
  // workspace layout (units of M1 f16 elems); overlays reuse dead regions:
  //  [0..8)    x_hi (dead after QKV gemm)     -> x1b overlay (live to fuseout)
  //  [8..20)   wqkv_hi (dead after QKV)
  //  [20..24)  wo_hi (dead after Wo)
  //  [24..40)  wup_hi (dead after Up)         -> p0 overlay (8M floats)
  //  [40..56)  wdn_hi (live to Down)
  //  [56..88)  q_hi/k_hi/q_lo/k_lo (dead after attn) -> hb overlay [56..88)
  //  [88..96)  vp (V proj; attn out; dead after Wo)  -> p1 overlay [88..104)
  //  [96..104) vtb (dead after attn)
  f16* x_hi    = W + 0 * M1;
  f16* wqkv_hi = W + 8 * M1;
  f16* wo_hi   = W + 20 * M1;
  f16* wup_hi  = W + 24 * M1;
  f16* wdn_hi  = W + 40 * M1;
  f16* q_hi    = W + 56 * M1;
  f16* q_lo    = W + 72 * M1;
  f16* vp      = W + 88 * M1;
  f16* vtb     = W + 96 * M1;
  // overlays (checked against live sets per stage):
  f16* x1b   = x_hi;                  // [0..8)  written by Wo, read by Up+fuseout
  float* p0  = (float*)(W + 24 * M1); // [24..40) — wup dead at Down
  f16* hb    = W + 56 * M1;           // [56..88) — q/k hi/lo dead after attn
  float* p1  = (float*)(W + 88 * M1); // [88..104) — vp/vtb dead after Wo
  f16* attno = vp;
  if (ws_size < (size_t)104 * M1 * sizeof(f16)) return;  // 208 MB

  auto cg = [](size_t n4) { size_t g = (n4 + 255) / 256; return (unsigned)(g > 2048 ? 2048 : g); };
  dim3 b256(256);
  k_cast<<<cg(2 * M1), b256, 0, stream>>>(x, x_hi, (int)(2 * M1));
  k_cast4<<<dim3(cg(1 * M1), 4), b256, 0, stream>>>(
      Wq, Wk, Wv, Wo,
      wqkv_hi, wqkv_hi + 4 * M1, wqkv_hi + 8 * M1, wo_hi, (int)(1 * M1));
  k_cast2w<<<dim3(cg(4 * M1), 2), b256, 0, stream>>>(
      Wup, Wdn, wup_hi, wdn_hi, (int)(4 * M1));

  // fused Q+K+V projection: single-pass f16, split (hi+lo) OUTPUT for Q,K.
  gemm_nt<0, 1, 64><<<dim3(48, 32), b256, 0, stream>>>(
      x_hi, wqkv_hi, 2048, 2048, 6144,
      nullptr, nullptr, nullptr, nullptr, q_hi, q_lo, vp);
  k_transpose_v<<<dim3(32, 2, 32), b256, 0, stream>>>(vp, vtb);
  k_attn<<<dim3(16, 32), b256, 0, stream>>>(
      q_hi, q_lo, q_hi + 8 * M1, q_lo + 8 * M1, vtb, attno);
  // Wo projection + residual -> x1b (f16)
  gemm_nt<1, 0, 64><<<dim3(16, 32), b256, 0, stream>>>(
      attno, wo_hi, 2048, 2048, 2048,
      x, nullptr, nullptr, nullptr, x1b, nullptr, nullptr);
  // Up + bias + relu -> hb
  gemm_nt<2, 0, 64><<<dim3(64, 32), b256, 0, stream>>>(
      x1b, wup_hi, 2048, 2048, 8192,
      nullptr, bup, nullptr, nullptr, hb, nullptr, nullptr);
  // Down, K split 2x -> f32 partials
  gemm_nt<3, 0, 64><<<dim3(16, 32, 2), b256, 0, stream>>>(
      hb, wdn_hi, 4096, 8192, 2048,
      nullptr, nullptr, p0, p1, nullptr, nullptr, nullptr);
  // out = f32(x1b) + p0 + p1
  k_fuseout<<<2048, b256, 0, stream>>>(x1b, p0, p1, out, (int)(2 * M1));
}

// Round 10
// 870.072 us; speedup vs baseline: 1.1526x; 1.1526x over previous
//
#include <hip/hip_runtime.h>
#include <stdint.h>

typedef _Float16 f16;
typedef __attribute__((ext_vector_type(8))) _Float16 f16x8;
typedef __attribute__((ext_vector_type(4))) _Float16 f16x4;
typedef __attribute__((ext_vector_type(4))) float f32x4;

// async global->LDS, 16B per lane. LDS dest is wave-uniform base (+lane*16 in HW).
__device__ __forceinline__ void gload16(void* lds, const void* gc) {
  void* g = const_cast<void*>(gc);
  __builtin_amdgcn_global_load_lds((__attribute__((address_space(1))) void*)g,
                                   (__attribute__((address_space(3))) void*)lds,
                                   16, 0, 0);
}

// ---------------- f32 -> f16 cast (plain) ----------------
__global__ __launch_bounds__(256) void k_cast(const float* __restrict__ in,
                                              f16* __restrict__ out, int n4) {
  int stride = gridDim.x * blockDim.x;
  for (int i = blockIdx.x * blockDim.x + threadIdx.x; i < n4; i += stride) {
    float4 v = ((const float4*)in)[i];
    f16x4 o;
    o[0] = (f16)v.x; o[1] = (f16)v.y; o[2] = (f16)v.z; o[3] = (f16)v.w;
    ((f16x4*)out)[i] = o;
  }
}

// 4 independent cast jobs selected by blockIdx.y (equal sizes)
__global__ __launch_bounds__(256) void k_cast4(const float* __restrict__ s0, const float* __restrict__ s1,
                                               const float* __restrict__ s2, const float* __restrict__ s3,
                                               f16* __restrict__ d0, f16* __restrict__ d1,
                                               f16* __restrict__ d2, f16* __restrict__ d3, int n4) {
  const int which = blockIdx.y;
  const float* in = which == 0 ? s0 : which == 1 ? s1 : which == 2 ? s2 : s3;
  f16* out = which == 0 ? d0 : which == 1 ? d1 : which == 2 ? d2 : d3;
  int stride = gridDim.x * blockDim.x;
  for (int i = blockIdx.x * blockDim.x + threadIdx.x; i < n4; i += stride) {
    float4 v = ((const float4*)in)[i];
    f16x4 o;
    o[0] = (f16)v.x; o[1] = (f16)v.y; o[2] = (f16)v.z; o[3] = (f16)v.w;
    ((f16x4*)out)[i] = o;
  }
}

// 2 independent cast jobs selected by blockIdx.y
__global__ __launch_bounds__(256) void k_cast2w(const float* __restrict__ s0, const float* __restrict__ s1,
                                                f16* __restrict__ d0, f16* __restrict__ d1, int n4) {
  const int which = blockIdx.y;
  const float* in = which == 0 ? s0 : s1;
  f16* out = which == 0 ? d0 : d1;
  int stride = gridDim.x * blockDim.x;
  for (int i = blockIdx.x * blockDim.x + threadIdx.x; i < n4; i += stride) {
    float4 v = ((const float4*)in)[i];
    f16x4 o;
    o[0] = (f16)v.x; o[1] = (f16)v.y; o[2] = (f16)v.z; o[3] = (f16)v.w;
    ((f16x4*)out)[i] = o;
  }
}

// ---------------- V transpose: [BH][L][128] -> [BH][128][L] ----------------
__global__ __launch_bounds__(256) void k_transpose_v(const f16* __restrict__ vp,
                                                     f16* __restrict__ vt) {
  __shared__ __attribute__((aligned(16))) f16 tile[64][66];
  const int lt = blockIdx.x, dt = blockIdx.y, bh = blockIdx.z;
  const int t = threadIdx.x;
  const int r = t >> 3, c = 8 * (t & 7);
  const f16* src = vp + ((size_t)bh * 2048 + lt * 64) * 128 + dt * 64;
#pragma unroll
  for (int i = 0; i < 2; ++i) {
    union { f16x8 v; unsigned u[4]; } uu;
    uu.v = *(const f16x8*)&src[(size_t)(i * 32 + r) * 128 + c];
#pragma unroll
    for (int j = 0; j < 4; ++j)
      *(unsigned*)&tile[i * 32 + r][c + 2 * j] = uu.u[j];
  }
  __syncthreads();
  f16* dst = vt + ((size_t)bh * 128 + dt * 64) * 2048 + lt * 64;
#pragma unroll
  for (int i = 0; i < 2; ++i) {
    const int dr = i * 32 + r;
    f16x8 o;
#pragma unroll
    for (int e = 0; e < 8; ++e) o[e] = tile[c + e][dr];
    *(f16x8*)&dst[(size_t)dr * 2048 + c] = o;
  }
}

// ---------------- final fuse: out = f32(x1b) + p0 + p1 ----------------
__global__ __launch_bounds__(256) void k_fuseout(const f16* __restrict__ x1b,
                                                 const float* __restrict__ p0,
                                                 const float* __restrict__ p1,
                                                 float* __restrict__ out, int n4) {
  int stride = gridDim.x * blockDim.x;
  for (int i = blockIdx.x * blockDim.x + threadIdx.x; i < n4; i += stride) {
    float4 a = ((const float4*)p0)[i];
    float4 b = ((const float4*)p1)[i];
    f16x4 xb = ((const f16x4*)x1b)[i];
    float4 o;
    o.x = (float)xb[0] + a.x + b.x;
    o.y = (float)xb[1] + a.y + b.y;
    o.z = (float)xb[2] + a.z + b.z;
    o.w = (float)xb[3] + a.w + b.w;
    ((float4*)out)[i] = o;
  }
}

// ---------------- NT GEMM: C[M,N] = A[M,K] @ B[N,K]^T, fused epilogues ----------------
// EPI 0: QKV -> which=gcol>>11: 0,1 -> outb/outb_lo (hi+lo split storage) at
//        which*8M in [B,H,L,DH] layout; 2 -> outv (plain f16) same layout.
// EPI 1: Wo   -> outb = f16(res[idx] + C)
// EPI 2: Up   -> outb = f16(relu(C + bias[col]))
// EPI 3: Down partial -> (z ? outf2 : outf)[idx] = C   (f32, no residual)
template <int EPI, int SPLITOUT, int BK>
__global__ __launch_bounds__(256, 4) void gemm_nt(const f16* __restrict__ A,
                                                  const f16* __restrict__ B,
                                                  int Kit, int ld, int N,
                                                  const float* __restrict__ res,
                                                  const float* __restrict__ bias,
                                                  float* __restrict__ outf,
                                                  float* __restrict__ outf2,
                                                  f16* __restrict__ outb,
                                                  f16* __restrict__ outb_lo,
                                                  f16* __restrict__ outv) {
  constexpr int TSZ = 128 * BK;
  constexpr int CH  = 2048;
  constexpr int RPC = CH / BK;
  constexpr int NCH = 128 / RPC;
  constexpr int CW  = BK / 8;
  __shared__ __attribute__((aligned(16))) f16 As[TSZ];
  __shared__ __attribute__((aligned(16))) f16 Bs[TSZ];
  const int t = threadIdx.x;
  const int l = t & 63;
  const int w = t >> 6;
  const int wr = w >> 1, wc = w & 1;

  // XCD-aware bijective swizzle (nwg % 8 == 0 for all our grids)
  const int nwg = gridDim.x * gridDim.y;
  const int id = blockIdx.y * gridDim.x + blockIdx.x;
  const int sw = (id & 7) * (nwg >> 3) + (id >> 3);
  const int bn = sw % gridDim.x;
  const int bm = sw / gridDim.x;
  const int k0 = blockIdx.z * Kit;

  f32x4 acc[4][4] = {};

  const size_t aoff = (size_t)bm * 128 * ld + k0;
  const size_t boff = (size_t)bn * 128 * ld + k0;

  const int sr = t / CW;
  const int sc = 8 * (t % CW);
  const int lbase = w * 512;

  const int lr = l & 15, lq = l >> 4;
  const int nk = Kit / BK;
  for (int kt = 0; kt < nk; ++kt) {
    const size_t gbase = (size_t)kt * BK + (size_t)sr * ld + sc;
#pragma unroll
    for (int j = 0; j < NCH; ++j) {
      gload16(As + j * CH + lbase, A + aoff + (size_t)j * RPC * ld + gbase);
      gload16(Bs + j * CH + lbase, B + boff + (size_t)j * RPC * ld + gbase);
    }
    __syncthreads();
#pragma unroll
    for (int kk = 0; kk < BK / 32; ++kk) {
      f16x8 af[4], bfr[4];
#pragma unroll
      for (int m = 0; m < 4; ++m)
        af[m] = *(const f16x8*)&As[(wr * 64 + m * 16 + lr) * BK + kk * 32 + 8 * lq];
#pragma unroll
      for (int n = 0; n < 4; ++n)
        bfr[n] = *(const f16x8*)&Bs[(wc * 64 + n * 16 + lr) * BK + kk * 32 + 8 * lq];
#pragma unroll
      for (int m = 0; m < 4; ++m)
#pragma unroll
        for (int n = 0; n < 4; ++n)
          acc[m][n] = __builtin_amdgcn_mfma_f32_16x16x32_f16(af[m], bfr[n], acc[m][n], 0, 0, 0);
    }
    __syncthreads();
  }

  const size_t QKS = (size_t)8 << 20;
#pragma unroll
  for (int m = 0; m < 4; ++m) {
#pragma unroll
    for (int r = 0; r < 4; ++r) {
      const int grow = bm * 128 + wr * 64 + m * 16 + lq * 4 + r;
#pragma unroll
      for (int n = 0; n < 4; ++n) {
        const int gcol = bn * 128 + wc * 64 + n * 16 + lr;
        const float v = acc[m][n][r];
        if constexpr (EPI == 0) {
          const int which = gcol >> 11;
          const int hcol = gcol & 2047;
          const int bb = grow >> 11, ll = grow & 2047;
          const int hh = hcol >> 7, dh = hcol & 127;
          const size_t idx = ((size_t)((bb * 16 + hh) * 2048 + ll) << 7) + dh;
          const f16 hv = (f16)v;
          if (which == 2) {
            outv[idx] = hv;
          } else {
            outb[which * QKS + idx] = hv;
            if constexpr (SPLITOUT) outb_lo[which * QKS + idx] = (f16)(v - (float)hv);
          }
        } else if constexpr (EPI == 1) {
          const size_t idx = (size_t)grow * N + gcol;
          outb[idx] = (f16)(res[idx] + v);
        } else if constexpr (EPI == 2) {
          const size_t idx = (size_t)grow * N + gcol;
          outb[idx] = (f16)fmaxf(v + bias[gcol], 0.f);
        } else {
          const size_t idx = (size_t)grow * N + gcol;
          (blockIdx.z ? outf2 : outf)[idx] = v;
        }
      }
    }
  }
}

// ---------------- causal flash attention ----------------
// Paired complementary q-tiles (qtA=31-bx, qtB=bx) with MERGED inner loops:
// each K/V fragment LDS read feeds both q-tile sets. Split-precision QK^T
// (3-pass), defer-max rescale. Staging temps are TRANSIENT (die at ds_write)
// to stay under the VGPR budget — round-9's cross-loop prefetch spilled.
__global__ __launch_bounds__(256) void k_attn(const f16* __restrict__ q_hi,
                                              const f16* __restrict__ q_lo,
                                              const f16* __restrict__ k_hi,
                                              const f16* __restrict__ k_lo,
                                              const f16* __restrict__ vtp,
                                              f16* __restrict__ op) {
  __shared__ __attribute__((aligned(16))) f16 Ks_hi[64 * 136];
  __shared__ __attribute__((aligned(16))) f16 Ks_lo[64 * 136];
  __shared__ __attribute__((aligned(16))) f16 Vs[128 * 72];
  __shared__ __attribute__((aligned(16))) f16 PsA[4][16 * 72];
  __shared__ __attribute__((aligned(16))) f16 PsB[4][16 * 72];
  const int t = threadIdx.x, l = t & 63, w = t >> 6;
  const int qtA = 31 - (int)blockIdx.x;  // 16..31
  const int qtB = (int)blockIdx.x;       // 15..0
  const int bh = blockIdx.y;
  const int qA0 = qtA * 64, qB0 = qtB * 64;
  const int lr = l & 15, lq = l >> 4;

  const f16* qhp = q_hi + (size_t)bh * 2048 * 128;
  const f16* qlp = q_lo + (size_t)bh * 2048 * 128;
  const f16* khp = k_hi + (size_t)bh * 2048 * 128;
  const f16* klp = k_lo + (size_t)bh * 2048 * 128;
  const f16* vhp = vtp + (size_t)bh * 128 * 2048;

  const int krow = t >> 4, kcol8 = 8 * (t & 15);
  const int vrow = t >> 3, vcol8 = 8 * (t & 7);

  f16x8 aqhA[4], aqlA[4], aqhB[4], aqlB[4];
#pragma unroll
  for (int c = 0; c < 4; ++c) {
    const size_t qiA = (size_t)(qA0 + w * 16 + lr) * 128 + c * 32 + 8 * lq;
    const size_t qiB = (size_t)(qB0 + w * 16 + lr) * 128 + c * 32 + 8 * lq;
    aqhA[c] = *(const f16x8*)&qhp[qiA];
    aqlA[c] = *(const f16x8*)&qlp[qiA];
    aqhB[c] = *(const f16x8*)&qhp[qiB];
    aqlB[c] = *(const f16x8*)&qlp[qiB];
  }

  f32x4 accA[8] = {}, accB[8] = {};
  float mrA[4], srA[4], mrB[4], srB[4];
#pragma unroll
  for (int r = 0; r < 4; ++r) {
    mrA[r] = -1e30f; srA[r] = 0.f;
    mrB[r] = -1e30f; srB[r] = 0.f;
  }

  // softmax + P-store for one q-set (unshared VALU work); defer-max rescale.
  auto softmax = [&](f32x4 (&s)[4], f32x4 (&acc)[8], float (&mr)[4], float (&sr)[4],
                     f16 (&Pw)[16 * 72]) {
    float mx[4];
#pragma unroll
    for (int r = 0; r < 4; ++r) {
      float m = fmaxf(fmaxf(s[0][r], s[1][r]), fmaxf(s[2][r], s[3][r]));
#pragma unroll
      for (int off = 1; off < 16; off <<= 1)
        m = fmaxf(m, __shfl_xor(m, off));
      mx[r] = m;
    }
    bool grew = false;
#pragma unroll
    for (int r = 0; r < 4; ++r) grew = grew || (mx[r] > mr[r] + 8.f);
    if (__any(grew)) {  // rescale to new max (wave-uniform branch)
      float scale[4];
#pragma unroll
      for (int r = 0; r < 4; ++r) {
        const float mnew = fmaxf(mr[r], mx[r]);
        scale[r] = __expf(mr[r] - mnew);
        mr[r] = mnew;
        sr[r] *= scale[r];
      }
#pragma unroll
      for (int nt = 0; nt < 8; ++nt)
#pragma unroll
        for (int r = 0; r < 4; ++r)
          acc[nt][r] *= scale[r];
    }
    float tsum[4] = {0.f, 0.f, 0.f, 0.f};
#pragma unroll
    for (int nt = 0; nt < 4; ++nt)
#pragma unroll
      for (int r = 0; r < 4; ++r) {
        const float p = __expf(s[nt][r] - mr[r]);  // bounded by e^8 when deferred
        tsum[r] += p;
        Pw[(lq * 4 + r) * 72 + nt * 16 + lr] = (f16)p;
      }
#pragma unroll
    for (int r = 0; r < 4; ++r) {
      float ts = tsum[r];
#pragma unroll
      for (int off = 1; off < 16; off <<= 1)
        ts += __shfl_xor(ts, off);
      sr[r] += ts;
    }
  };

  for (int kt = 0; kt <= qtA; ++kt) {
    // this tile's global loads: transient temps, die at the ds_write below
    f16x8 tkh[4], tkl[4], tv[4];
#pragma unroll
    for (int i = 0; i < 4; ++i) {
      const size_t ki = (size_t)(kt * 64 + i * 16 + krow) * 128 + kcol8;
      tkh[i] = *(const f16x8*)&khp[ki];
      tkl[i] = *(const f16x8*)&klp[ki];
      tv[i] = *(const f16x8*)&vhp[(size_t)(i * 32 + vrow) * 2048 + kt * 64 + vcol8];
    }
    __syncthreads();  // prior tile's LDS reads done
#pragma unroll
    for (int i = 0; i < 4; ++i) {
      const int li = (i * 16 + krow) * 136 + kcol8;
      *(f16x8*)&Ks_hi[li] = tkh[i];
      *(f16x8*)&Ks_lo[li] = tkl[i];
      *(f16x8*)&Vs[(i * 32 + vrow) * 72 + vcol8] = tv[i];
    }
    __syncthreads();

    const bool doB = (kt <= qtB);

    // --- merged QK^T: each K-fragment read feeds both q-sets ---
    f32x4 sA[4], sB[4];
    __builtin_amdgcn_s_setprio(1);
#pragma unroll
    for (int nt = 0; nt < 4; ++nt) {
      f32x4 zhA = {}, zlA = {}, zhB = {}, zlB = {};
#pragma unroll
      for (int kc = 0; kc < 4; ++kc) {
        const int li = (nt * 16 + lr) * 136 + kc * 32 + 8 * lq;
        f16x8 bh_ = *(const f16x8*)&Ks_hi[li];
        f16x8 bl_ = *(const f16x8*)&Ks_lo[li];
        zhA = __builtin_amdgcn_mfma_f32_16x16x32_f16(aqhA[kc], bh_, zhA, 0, 0, 0);
        zlA = __builtin_amdgcn_mfma_f32_16x16x32_f16(aqlA[kc], bh_, zlA, 0, 0, 0);
        zlA = __builtin_amdgcn_mfma_f32_16x16x32_f16(aqhA[kc], bl_, zlA, 0, 0, 0);
        if (doB) {
          zhB = __builtin_amdgcn_mfma_f32_16x16x32_f16(aqhB[kc], bh_, zhB, 0, 0, 0);
          zlB = __builtin_amdgcn_mfma_f32_16x16x32_f16(aqlB[kc], bh_, zlB, 0, 0, 0);
          zlB = __builtin_amdgcn_mfma_f32_16x16x32_f16(aqhB[kc], bl_, zlB, 0, 0, 0);
        }
      }
#pragma unroll
      for (int r = 0; r < 4; ++r) {
        sA[nt][r] = zhA[r] + zlA[r];
        sB[nt][r] = zhB[r] + zlB[r];
      }
    }
    __builtin_amdgcn_s_setprio(0);

    // causal masks (diagonal tiles only)
    if (kt == qtA) {
#pragma unroll
      for (int nt = 0; nt < 4; ++nt)
#pragma unroll
        for (int r = 0; r < 4; ++r)
          if (kt * 64 + nt * 16 + lr > qA0 + w * 16 + lq * 4 + r) sA[nt][r] = -1e30f;
    }
    if (doB && kt == qtB) {
#pragma unroll
      for (int nt = 0; nt < 4; ++nt)
#pragma unroll
        for (int r = 0; r < 4; ++r)
          if (kt * 64 + nt * 16 + lr > qB0 + w * 16 + lq * 4 + r) sB[nt][r] = -1e30f;
    }

    softmax(sA, accA, mrA, srA, PsA[w]);
    if (doB) softmax(sB, accB, mrB, srB, PsB[w]);

    // --- merged PV: each V-fragment read feeds both q-sets ---
    __builtin_amdgcn_s_setprio(1);
#pragma unroll
    for (int kc = 0; kc < 2; ++kc) {
      f16x8 apA = *(const f16x8*)&PsA[w][lr * 72 + kc * 32 + 8 * lq];
      f16x8 apB = *(const f16x8*)&PsB[w][lr * 72 + kc * 32 + 8 * lq];
#pragma unroll
      for (int nt = 0; nt < 8; ++nt) {
        f16x8 bv = *(const f16x8*)&Vs[(nt * 16 + lr) * 72 + kc * 32 + 8 * lq];
        accA[nt] = __builtin_amdgcn_mfma_f32_16x16x32_f16(apA, bv, accA[nt], 0, 0, 0);
        if (doB) accB[nt] = __builtin_amdgcn_mfma_f32_16x16x32_f16(apB, bv, accB[nt], 0, 0, 0);
      }
    }
    __builtin_amdgcn_s_setprio(0);
  }

  const int bb = bh >> 4, hh = bh & 15;
  auto wout = [&](f32x4 (&acc)[8], float (&sr)[4], int q0) {
#pragma unroll
    for (int r = 0; r < 4; ++r) {
      const float inv = 1.f / sr[r];
      const size_t row = (size_t)(bb * 2048 + q0 + w * 16 + lq * 4 + r);
#pragma unroll
      for (int nt = 0; nt < 8; ++nt)
        op[row * 2048 + hh * 128 + nt * 16 + lr] = (f16)(acc[nt][r] * inv);
    }
  };
  wout(accA, srA, qA0);
  wout(accB, srB, qB0);
}

extern "C" void kernel_launch(void* const* d_in, const int* in_sizes, int n_in,
                              void* d_out, int out_size, void* d_ws, size_t ws_size,
                              hipStream_t stream) {
  const float* x   = (const float*)d_in[0];
  const float* Wq  = (const float*)d_in[2];
  const float* Wk  = (const float*)d_in[3];
  const float* Wv  = (const float*)d_in[4];
  const float* Wo  = (const float*)d_in[5];
  const float* Wup = (const float*)d_in[6];
  const float* bup = (const float*)d_in[7];
  const float* Wdn = (const float*)d_in[8];
  float* out = (float*)d_out;

  const size_t M1 = 1u << 20;
  f16* W = (f16*)d_ws;
  // workspace layout (units of M1 f16 elems); overlays reuse dead regions:
  //  [0..8)    x_hi (dead after QKV gemm)     -> x1b overlay (live to fuseout)
  //  [8..20)   wqkv_hi (dead after QKV)
  //  [20..24)  wo_hi (dead after Wo)
  //  [24..40)  wup_hi (dead after Up)         -> p0 overlay (8M floats)
  //  [40..56)  wdn_hi (live to Down)
  //  [56..88)  q_hi/k_hi/q_lo/k_lo (dead after attn) -> hb overlay [56..88)
  //  [88..96)  vp (V proj; attn out; dead after Wo)  -> p1 overlay [88..104)
  //  [96..104) vtb (dead after attn)
  f16* x_hi    = W + 0 * M1;
  f16* wqkv_hi = W + 8 * M1;
  f16* wo_hi   = W + 20 * M1;
  f16* wup_hi  = W + 24 * M1;
  f16* wdn_hi  = W + 40 * M1;
  f16* q_hi    = W + 56 * M1;
  f16* q_lo    = W + 72 * M1;
  f16* vp      = W + 88 * M1;
  f16* vtb     = W + 96 * M1;
  // overlays (checked against live sets per stage):
  f16* x1b   = x_hi;                  // [0..8)  written by Wo, read by Up+fuseout
  float* p0  = (float*)(W + 24 * M1); // [24..40) — wup dead at Down
  f16* hb    = W + 56 * M1;           // [56..88) — q/k hi/lo dead after attn
  float* p1  = (float*)(W + 88 * M1); // [88..104) — vp/vtb dead after Wo
  f16* attno = vp;
  if (ws_size < (size_t)104 * M1 * sizeof(f16)) return;  // 208 MB

  auto cg = [](size_t n4) { size_t g = (n4 + 255) / 256; return (unsigned)(g > 2048 ? 2048 : g); };
  dim3 b256(256);
  k_cast<<<cg(2 * M1), b256, 0, stream>>>(x, x_hi, (int)(2 * M1));
  k_cast4<<<dim3(cg(1 * M1), 4), b256, 0, stream>>>(
      Wq, Wk, Wv, Wo,
      wqkv_hi, wqkv_hi + 4 * M1, wqkv_hi + 8 * M1, wo_hi, (int)(1 * M1));
  k_cast2w<<<dim3(cg(4 * M1), 2), b256, 0, stream>>>(
      Wup, Wdn, wup_hi, wdn_hi, (int)(4 * M1));

  // fused Q+K+V projection: single-pass f16, split (hi+lo) OUTPUT for Q,K.
  gemm_nt<0, 1, 64><<<dim3(48, 32), b256, 0, stream>>>(
      x_hi, wqkv_hi, 2048, 2048, 6144,
      nullptr, nullptr, nullptr, nullptr, q_hi, q_lo, vp);
  k_transpose_v<<<dim3(32, 2, 32), b256, 0, stream>>>(vp, vtb);
  k_attn<<<dim3(16, 32), b256, 0, stream>>>(
      q_hi, q_lo, q_hi + 8 * M1, q_lo + 8 * M1, vtb, attno);
  // Wo projection + residual -> x1b (f16)
  gemm_nt<1, 0, 64><<<dim3(16, 32), b256, 0, stream>>>(
      attno, wo_hi, 2048, 2048, 2048,
      x, nullptr, nullptr, nullptr, x1b, nullptr, nullptr);
  // Up + bias + relu -> hb
  gemm_nt<2, 0, 64><<<dim3(64, 32), b256, 0, stream>>>(
      x1b, wup_hi, 2048, 2048, 8192,
      nullptr, bup, nullptr, nullptr, hb, nullptr, nullptr);
  // Down, K split 2x -> f32 partials
  gemm_nt<3, 0, 64><<<dim3(16, 32, 2), b256, 0, stream>>>(
      hb, wdn_hi, 4096, 8192, 2048,
      nullptr, nullptr, p0, p1, nullptr, nullptr, nullptr);
  // out = f32(x1b) + p0 + p1
  k_fuseout<<<2048, b256, 0, stream>>>(x1b, p0, p1, out, (int)(2 * M1));
}